// Round 1
// baseline (224.456 us; speedup 1.0000x reference)
//
#include <hip/hip_runtime.h>

typedef unsigned short u16;
typedef unsigned int u32;
typedef unsigned long long u64;
typedef __bf16 bf16x8 __attribute__((ext_vector_type(8)));
typedef float f32x4 __attribute__((ext_vector_type(4)));

#define B_ 2
#define N_ 2048
#define C_ 768
#define H_ 12
#define M_ 4096  // B_*N_

static __device__ __forceinline__ u16 f2bf(float f) {
  u32 u = __builtin_bit_cast(u32, f);
  u32 r = u + 0x7fffu + ((u >> 16) & 1u);  // RNE
  return (u16)(r >> 16);
}
static __device__ __forceinline__ float bf2f(u16 h) {
  u32 u = ((u32)h) << 16;
  return __builtin_bit_cast(float, u);
}

// async global->LDS, 16B per lane; LDS dest is wave-uniform base (HW adds lane*16)
static __device__ __forceinline__ void gload16(const void* g, void* lds_base) {
  __builtin_amdgcn_global_load_lds(
      (__attribute__((address_space(1))) void*)(u64)(g),
      (__attribute__((address_space(3))) void*)(u32)(u64)(lds_base), 16, 0, 0);
}

// ---------------- fp32 -> bf16 elementwise (x) ----------------
__global__ __launch_bounds__(256) void k_cvt4(const float* __restrict__ x,
                                              u16* __restrict__ xb, int n4) {
  int i = blockIdx.x * 256 + threadIdx.x;
  if (i >= n4) return;
  float4 v = ((const float4*)x)[i];
  ushort4 o;
  o.x = f2bf(v.x); o.y = f2bf(v.y); o.z = f2bf(v.z); o.w = f2bf(v.w);
  ((ushort4*)xb)[i] = o;
}

// ---------------- W[K][N] fp32 -> Wt[N][K] bf16 ----------------
__global__ __launch_bounds__(256) void k_tconv(const float* __restrict__ W,
                                               u16* __restrict__ Wt, int K, int N) {
  __shared__ float t[32][33];
  int n0 = blockIdx.x * 32, k0 = blockIdx.y * 32;
  int tx = threadIdx.x, ty = threadIdx.y;  // 32 x 8
#pragma unroll
  for (int i = 0; i < 4; i++)
    t[ty + i * 8][tx] = W[(u64)(k0 + ty + i * 8) * N + n0 + tx];
  __syncthreads();
#pragma unroll
  for (int i = 0; i < 4; i++)
    Wt[(u64)(n0 + ty + i * 8) * K + k0 + tx] = f2bf(t[tx][ty + i * 8]);
}

// ---------------- GEMM: C[M,N] = A[M,K] @ Bt[N,K]^T (bf16 MFMA) ----------------
// EPI 0: C bf16 row-major [ld=Nsz]
// EPI 1: C^T bf16 [Nsz][Msz]  (transposed write, vectorized 4-row pack)
// EPI 2: C fp32 row-major + bias
template <int EPI>
__global__ __launch_bounds__(256) void k_gemm(const u16* __restrict__ A,
                                              const u16* __restrict__ Bt,
                                              void* __restrict__ Cout,
                                              const float* __restrict__ bias,
                                              int Msz, int Nsz, int Ksz) {
  __shared__ u16 As[128 * 32];
  __shared__ u16 Bs[128 * 32];
  const int t = threadIdx.x;
  const int w = t >> 6, l = t & 63;
  const int wr = w >> 1, wc = w & 1;
  const int la = l & 15, lg = l >> 4;
  const int srow = l >> 2, scb = (l & 3) << 4;  // staging: 4 lanes per 64B row

  f32x4 acc[4][4];
#pragma unroll
  for (int i = 0; i < 4; i++)
#pragma unroll
    for (int j = 0; j < 4; j++) acc[i][j] = f32x4{0.f, 0.f, 0.f, 0.f};

  const u16* Ag = A + (u64)(blockIdx.x * 128) * Ksz;
  const u16* Bg = Bt + (u64)(blockIdx.y * 128) * Ksz;

  for (int k0 = 0; k0 < Ksz; k0 += 32) {
#pragma unroll
    for (int j = 0; j < 2; j++) {
      int r = (w * 2 + j) * 16 + srow;
      gload16((const char*)(Ag + (u64)r * Ksz + k0) + scb,
              (char*)As + (w * 2 + j) * 1024);
      gload16((const char*)(Bg + (u64)r * Ksz + k0) + scb,
              (char*)Bs + (w * 2 + j) * 1024);
    }
    __syncthreads();
    bf16x8 af[4], bfr[4];
#pragma unroll
    for (int m = 0; m < 4; m++)
      af[m] = *(const bf16x8*)(As + (wr * 64 + m * 16 + la) * 32 + lg * 8);
#pragma unroll
    for (int n = 0; n < 4; n++)
      bfr[n] = *(const bf16x8*)(Bs + (wc * 64 + n * 16 + la) * 32 + lg * 8);
#pragma unroll
    for (int m = 0; m < 4; m++)
#pragma unroll
      for (int n = 0; n < 4; n++)
        acc[m][n] =
            __builtin_amdgcn_mfma_f32_16x16x32_bf16(af[m], bfr[n], acc[m][n], 0, 0, 0);
    __syncthreads();
  }

#pragma unroll
  for (int m = 0; m < 4; m++) {
#pragma unroll
    for (int n = 0; n < 4; n++) {
      int grow0 = blockIdx.x * 128 + wr * 64 + m * 16 + lg * 4;
      int gcol = blockIdx.y * 128 + wc * 64 + n * 16 + la;
      if (EPI == 0) {
        u16* Cp = (u16*)Cout;
#pragma unroll
        for (int j = 0; j < 4; j++)
          Cp[(u64)(grow0 + j) * Nsz + gcol] = f2bf(acc[m][n][j]);
      } else if (EPI == 1) {
        u16* Cp = (u16*)Cout;
        ushort4 o;
        o.x = f2bf(acc[m][n][0]); o.y = f2bf(acc[m][n][1]);
        o.z = f2bf(acc[m][n][2]); o.w = f2bf(acc[m][n][3]);
        *(ushort4*)(Cp + (u64)gcol * Msz + grow0) = o;
      } else {
        float* Cp = (float*)Cout;
        float bb = bias[gcol];
#pragma unroll
        for (int j = 0; j < 4; j++)
          Cp[(u64)(grow0 + j) * Nsz + gcol] = acc[m][n][j] + bb;
      }
    }
  }
}

// ---------------- flash attention, one (qtile64, h, p, b) per block ----------------
// Qb,Kb: [4096][1536] bf16 (col = p*768 + h*64 + d). Vt: [768][4096] bf16 (row = h*64+d).
// O out: [2][4096][768] bf16.
__global__ __launch_bounds__(256) void k_attn(const u16* __restrict__ Qb,
                                              const u16* __restrict__ Kb,
                                              const u16* __restrict__ Vt,
                                              u16* __restrict__ O) {
  const int qt = blockIdx.x;
  const int h = blockIdx.y >> 1, p = blockIdx.y & 1;
  const int b = blockIdx.z;
  __shared__ u16 Ks[64 * 64];
  __shared__ u16 Vs[64 * 64];
  __shared__ u16 Ps[4][16 * 64];  // per-wave P scratch
  const int t = threadIdx.x, w = t >> 6, l = t & 63;
  const int la = l & 15, lg = l >> 4;

  // Q fragments in registers: wave w owns q rows qt*64+w*16 .. +15
  const u16* qp = Qb + (u64)(b * N_ + qt * 64 + w * 16 + la) * (2 * C_) + p * C_ +
                  h * 64 + lg * 8;
  bf16x8 qf0 = *(const bf16x8*)(qp);
  bf16x8 qf1 = *(const bf16x8*)(qp + 32);

  f32x4 oacc[4];
#pragma unroll
  for (int i = 0; i < 4; i++) oacc[i] = f32x4{0.f, 0.f, 0.f, 0.f};
  float m_run = -1e30f, l_run = 0.f;

  for (int kt = 0; kt < 32; kt++) {
    const int kv0 = kt * 64;
    // stage K (row=kv) and V (row=d) tiles, XOR-swizzled rows of 128B
#pragma unroll
    for (int j = 0; j < 2; j++) {
      int row = (w * 2 + j) * 8 + (l >> 3);
      int cb = (l & 7) << 4;
      const char* kg =
          (const char*)(Kb + (u64)(b * N_ + kv0 + row) * (2 * C_) + p * C_ + h * 64) + cb;
      const char* vg = (const char*)(Vt + (u64)(h * 64 + row) * M_ + b * N_ + kv0) + cb;
      uint4 kd = *(const uint4*)kg;
      uint4 vd = *(const uint4*)vg;
      int swz = cb ^ ((row & 7) << 4);
      *(uint4*)((char*)Ks + row * 128 + swz) = kd;
      *(uint4*)((char*)Vs + row * 128 + swz) = vd;
    }
    __syncthreads();

    // S^T[kv][q] = K @ Q^T   (lane holds q = la; kv = c*16 + 4*lg + j)
    f32x4 st[4];
#pragma unroll
    for (int c = 0; c < 4; c++) {
      int row = c * 16 + la;
      int sw = (row & 7) << 4;
      bf16x8 kf0 = *(const bf16x8*)((const char*)Ks + row * 128 + ((lg * 16) ^ sw));
      bf16x8 kf1 = *(const bf16x8*)((const char*)Ks + row * 128 + ((64 + lg * 16) ^ sw));
      f32x4 z = f32x4{0.f, 0.f, 0.f, 0.f};
      z = __builtin_amdgcn_mfma_f32_16x16x32_bf16(kf0, qf0, z, 0, 0, 0);
      z = __builtin_amdgcn_mfma_f32_16x16x32_bf16(kf1, qf1, z, 0, 0, 0);
      st[c] = z;
    }
#pragma unroll
    for (int c = 0; c < 4; c++) st[c] *= 0.125f;  // 1/sqrt(64)

    // online softmax (per q = la; combine the 4 lane-groups with xor-shuffles)
    float mloc = -1e30f;
#pragma unroll
    for (int c = 0; c < 4; c++)
#pragma unroll
      for (int j = 0; j < 4; j++) mloc = fmaxf(mloc, st[c][j]);
    mloc = fmaxf(mloc, __shfl_xor(mloc, 16, 64));
    mloc = fmaxf(mloc, __shfl_xor(mloc, 32, 64));
    float mnew = fmaxf(m_run, mloc);
    float corr = __expf(m_run - mnew);
    float ls = 0.f;
#pragma unroll
    for (int c = 0; c < 4; c++)
#pragma unroll
      for (int j = 0; j < 4; j++) {
        float e = __expf(st[c][j] - mnew);
        st[c][j] = e;
        ls += e;
      }
    ls += __shfl_xor(ls, 16, 64);
    ls += __shfl_xor(ls, 32, 64);
    l_run = l_run * corr + ls;
    m_run = mnew;

    // P -> per-wave LDS (swizzled), so PV can read A-layout fragments
    char* pw = (char*)Ps[w];
#pragma unroll
    for (int c = 0; c < 4; c++)
#pragma unroll
      for (int j = 0; j < 4; j++) {
        int kv = c * 16 + lg * 4 + j;
        *(u16*)(pw + la * 128 + (((kv * 2) ^ ((la & 7) << 4)))) = f2bf(st[c][j]);
      }

    // rescale O (O rows are q = 4*lg + j -> fetch corr from lane 4*lg+j)
    float corrT[4];
#pragma unroll
    for (int j = 0; j < 4; j++) corrT[j] = __shfl(corr, lg * 4 + j, 64);
#pragma unroll
    for (int cd = 0; cd < 4; cd++)
#pragma unroll
      for (int j = 0; j < 4; j++) oacc[cd][j] *= corrT[j];

    int sw2 = (la & 7) << 4;
    bf16x8 pf0 = *(const bf16x8*)(pw + la * 128 + ((lg * 16) ^ sw2));
    bf16x8 pf1 = *(const bf16x8*)(pw + la * 128 + ((64 + lg * 16) ^ sw2));
#pragma unroll
    for (int cd = 0; cd < 4; cd++) {
      int row = cd * 16 + la;  // d row in Vs
      int sw = (row & 7) << 4;
      bf16x8 v0 = *(const bf16x8*)((const char*)Vs + row * 128 + ((lg * 16) ^ sw));
      bf16x8 v1 = *(const bf16x8*)((const char*)Vs + row * 128 + ((64 + lg * 16) ^ sw));
      oacc[cd] = __builtin_amdgcn_mfma_f32_16x16x32_bf16(pf0, v0, oacc[cd], 0, 0, 0);
      oacc[cd] = __builtin_amdgcn_mfma_f32_16x16x32_bf16(pf1, v1, oacc[cd], 0, 0, 0);
    }
    __syncthreads();
  }

  float linv = 1.f / l_run;
  float lT[4];
#pragma unroll
  for (int j = 0; j < 4; j++) lT[j] = __shfl(linv, lg * 4 + j, 64);
  u16* Og = O + (u64)p * M_ * C_ + (u64)(b * N_ + qt * 64 + w * 16) * C_ + h * 64;
#pragma unroll
  for (int cd = 0; cd < 4; cd++)
#pragma unroll
    for (int j = 0; j < 4; j++)
      Og[(u64)(lg * 4 + j) * C_ + cd * 16 + la] = f2bf(oacc[cd][j] * lT[j]);
}

// ---------------- combine: Ob = O0 - exp(lambda_h)*O1 (bf16) ----------------
__global__ __launch_bounds__(256) void k_comb(const u16* __restrict__ O,
                                              const float* __restrict__ lamp,
                                              u16* __restrict__ Ob) {
  int i = blockIdx.x * 256 + threadIdx.x;  // quad index over M_*C_/4
  int col = (i * 4) % C_;
  float lam = __expf(lamp[col >> 6]);
  ushort4 a = ((const ushort4*)O)[i];
  ushort4 c = ((const ushort4*)(O + (u64)M_ * C_))[i];
  ushort4 o;
  o.x = f2bf(bf2f(a.x) - lam * bf2f(c.x));
  o.y = f2bf(bf2f(a.y) - lam * bf2f(c.y));
  o.z = f2bf(bf2f(a.z) - lam * bf2f(c.z));
  o.w = f2bf(bf2f(a.w) - lam * bf2f(c.w));
  ((ushort4*)Ob)[i] = o;
}

extern "C" void kernel_launch(void* const* d_in, const int* in_sizes, int n_in,
                              void* d_out, int out_size, void* d_ws, size_t ws_size,
                              hipStream_t stream) {
  const float* x = (const float*)d_in[0];
  const float* Wq = (const float*)d_in[1];
  const float* Wk = (const float*)d_in[2];
  const float* Wv = (const float*)d_in[3];
  const float* lamp = (const float*)d_in[4];
  const float* Wo = (const float*)d_in[5];
  const float* bo = (const float*)d_in[6];

  char* ws = (char*)d_ws;
  u16* xb = (u16*)ws;   ws += (u64)M_ * C_ * 2;        // x bf16 [4096][768]
  u16* wqt = (u16*)ws;  ws += (u64)2 * C_ * C_ * 2;    // Wq^T bf16 [1536][768]
  u16* wkt = (u16*)ws;  ws += (u64)2 * C_ * C_ * 2;    // Wk^T
  u16* wvt = (u16*)ws;  ws += (u64)C_ * C_ * 2;        // Wv^T [768][768]
  u16* wot = (u16*)ws;  ws += (u64)C_ * C_ * 2;        // Wo^T
  u16* Qb = (u16*)ws;   ws += (u64)M_ * 2 * C_ * 2;    // Q bf16 [4096][1536]
  u16* Kb = (u16*)ws;   ws += (u64)M_ * 2 * C_ * 2;    // K bf16
  u16* Vt = (u16*)ws;   ws += (u64)C_ * M_ * 2;        // V^T bf16 [768][4096]
  u16* O = (u16*)ws;    ws += (u64)2 * M_ * C_ * 2;    // attn out [2][4096][768] bf16
  u16* Ob = (u16*)ws;   ws += (u64)M_ * C_ * 2;        // combined bf16

  k_cvt4<<<dim3(M_ * C_ / 4 / 256), 256, 0, stream>>>(x, xb, M_ * C_ / 4);
  k_tconv<<<dim3(48, 24), dim3(32, 8), 0, stream>>>(Wq, wqt, 768, 1536);
  k_tconv<<<dim3(48, 24), dim3(32, 8), 0, stream>>>(Wk, wkt, 768, 1536);
  k_tconv<<<dim3(24, 24), dim3(32, 8), 0, stream>>>(Wv, wvt, 768, 768);
  k_tconv<<<dim3(24, 24), dim3(32, 8), 0, stream>>>(Wo, wot, 768, 768);
  k_gemm<0><<<dim3(32, 12), 256, 0, stream>>>(xb, wqt, Qb, nullptr, M_, 1536, 768);
  k_gemm<0><<<dim3(32, 12), 256, 0, stream>>>(xb, wkt, Kb, nullptr, M_, 1536, 768);
  k_gemm<1><<<dim3(32, 6), 256, 0, stream>>>(xb, wvt, Vt, nullptr, M_, 768, 768);
  k_attn<<<dim3(32, 24, 2), 256, 0, stream>>>(Qb, Kb, Vt, O);
  k_comb<<<dim3(M_ * C_ / 4 / 256), 256, 0, stream>>>(O, lamp, Ob);
  k_gemm<2><<<dim3(32, 6), 256, 0, stream>>>(Ob, wot, d_out, bo, M_, 768, 768);
}

// Round 2
// 166.782 us; speedup vs baseline: 1.3458x; 1.3458x over previous
//
#include <hip/hip_runtime.h>

typedef unsigned short u16;
typedef unsigned int u32;
typedef unsigned long long u64;
typedef __bf16 bf16x8 __attribute__((ext_vector_type(8)));
typedef float f32x4 __attribute__((ext_vector_type(4)));

#define B_ 2
#define N_ 2048
#define C_ 768
#define H_ 12
#define M_ 4096  // B_*N_

static __device__ __forceinline__ u16 f2bf(float f) {
  u32 u = __builtin_bit_cast(u32, f);
  u32 r = u + 0x7fffu + ((u >> 16) & 1u);  // RNE
  return (u16)(r >> 16);
}
static __device__ __forceinline__ float bf2f(u16 h) {
  u32 u = ((u32)h) << 16;
  return __builtin_bit_cast(float, u);
}
static __device__ __forceinline__ float fexp2(float x) {
#if __has_builtin(__builtin_amdgcn_exp2f)
  return __builtin_amdgcn_exp2f(x);
#else
  return __expf(x * 0.6931471805599453f);
#endif
}
static __device__ __forceinline__ u32 pack_bf16(float a, float b) {
  u32 r;
  asm("v_cvt_pk_bf16_f32 %0, %1, %2" : "=v"(r) : "v"(a), "v"(b));
  return r;
}

// async global->LDS, 16B per lane; LDS dest is wave-uniform base (HW adds lane*16)
static __device__ __forceinline__ void gload16(const void* g, void* lds_base) {
  __builtin_amdgcn_global_load_lds(
      (__attribute__((address_space(1))) void*)(u64)(g),
      (__attribute__((address_space(3))) void*)(u32)(u64)(lds_base), 16, 0, 0);
}

// ---------------- fp32 -> bf16 elementwise (x) ----------------
__global__ __launch_bounds__(256) void k_cvt4(const float* __restrict__ x,
                                              u16* __restrict__ xb, int n4) {
  int i = blockIdx.x * 256 + threadIdx.x;
  if (i >= n4) return;
  float4 v = ((const float4*)x)[i];
  ushort4 o;
  o.x = f2bf(v.x); o.y = f2bf(v.y); o.z = f2bf(v.z); o.w = f2bf(v.w);
  ((ushort4*)xb)[i] = o;
}

// ---------------- W[K][N] fp32 -> Wt[N][K] bf16, z selects (src, dst slab) ----------------
__global__ __launch_bounds__(256) void k_tconv2(const float* __restrict__ W0,
                                                const float* __restrict__ W1,
                                                u16* __restrict__ Wt, int K, int N) {
  const float* W = blockIdx.z ? W1 : W0;
  u16* dst = Wt + (u64)blockIdx.z * N * K;
  __shared__ float t[32][33];
  int n0 = blockIdx.x * 32, k0 = blockIdx.y * 32;
  int tx = threadIdx.x, ty = threadIdx.y;  // 32 x 8
#pragma unroll
  for (int i = 0; i < 4; i++)
    t[ty + i * 8][tx] = W[(u64)(k0 + ty + i * 8) * N + n0 + tx];
  __syncthreads();
#pragma unroll
  for (int i = 0; i < 4; i++)
    dst[(u64)(n0 + ty + i * 8) * K + k0 + tx] = f2bf(t[tx][ty + i * 8]);
}

// ---------------- GEMM: C[M,N] = A[M,K] @ Bt[N,K]^T (bf16 MFMA) ----------------
// EPI 0: C bf16 row-major [ld=Nsz]
// EPI 1: C^T bf16 [Nsz][Msz]  (transposed write, vectorized 4-row pack)
// EPI 2: C fp32 row-major + bias
template <int EPI>
__global__ __launch_bounds__(256) void k_gemm(const u16* __restrict__ A,
                                              const u16* __restrict__ Bt,
                                              void* __restrict__ Cout,
                                              const float* __restrict__ bias,
                                              int Msz, int Nsz, int Ksz) {
  __shared__ u16 As[128 * 32];
  __shared__ u16 Bs[128 * 32];
  const int t = threadIdx.x;
  const int w = t >> 6, l = t & 63;
  const int wr = w >> 1, wc = w & 1;
  const int la = l & 15, lg = l >> 4;
  const int srow = l >> 2, scb = (l & 3) << 4;  // staging: 4 lanes per 64B row

  f32x4 acc[4][4];
#pragma unroll
  for (int i = 0; i < 4; i++)
#pragma unroll
    for (int j = 0; j < 4; j++) acc[i][j] = f32x4{0.f, 0.f, 0.f, 0.f};

  const u16* Ag = A + (u64)(blockIdx.x * 128) * Ksz;
  const u16* Bg = Bt + (u64)(blockIdx.y * 128) * Ksz;

  for (int k0 = 0; k0 < Ksz; k0 += 32) {
#pragma unroll
    for (int j = 0; j < 2; j++) {
      int r = (w * 2 + j) * 16 + srow;
      gload16((const char*)(Ag + (u64)r * Ksz + k0) + scb,
              (char*)As + (w * 2 + j) * 1024);
      gload16((const char*)(Bg + (u64)r * Ksz + k0) + scb,
              (char*)Bs + (w * 2 + j) * 1024);
    }
    __syncthreads();
    bf16x8 af[4], bfr[4];
#pragma unroll
    for (int m = 0; m < 4; m++)
      af[m] = *(const bf16x8*)(As + (wr * 64 + m * 16 + la) * 32 + lg * 8);
#pragma unroll
    for (int n = 0; n < 4; n++)
      bfr[n] = *(const bf16x8*)(Bs + (wc * 64 + n * 16 + la) * 32 + lg * 8);
#pragma unroll
    for (int m = 0; m < 4; m++)
#pragma unroll
      for (int n = 0; n < 4; n++)
        acc[m][n] =
            __builtin_amdgcn_mfma_f32_16x16x32_bf16(af[m], bfr[n], acc[m][n], 0, 0, 0);
    __syncthreads();
  }

#pragma unroll
  for (int m = 0; m < 4; m++) {
#pragma unroll
    for (int n = 0; n < 4; n++) {
      int grow0 = blockIdx.x * 128 + wr * 64 + m * 16 + lg * 4;
      int gcol = blockIdx.y * 128 + wc * 64 + n * 16 + la;
      if (EPI == 0) {
        u16* Cp = (u16*)Cout;
#pragma unroll
        for (int j = 0; j < 4; j++)
          Cp[(u64)(grow0 + j) * Nsz + gcol] = f2bf(acc[m][n][j]);
      } else if (EPI == 1) {
        u16* Cp = (u16*)Cout;
        ushort4 o;
        o.x = f2bf(acc[m][n][0]); o.y = f2bf(acc[m][n][1]);
        o.z = f2bf(acc[m][n][2]); o.w = f2bf(acc[m][n][3]);
        *(ushort4*)(Cp + (u64)gcol * Msz + grow0) = o;
      } else {
        float* Cp = (float*)Cout;
        float bb = bias[gcol];
#pragma unroll
        for (int j = 0; j < 4; j++)
          Cp[(u64)(grow0 + j) * Nsz + gcol] = acc[m][n][j] + bb;
      }
    }
  }
}

// ---------------- fused dual-phase flash attention + combine ----------------
// QKb: [4096][3072] bf16 (Q cols p*768+h*64+d ; K cols 1536+p*768+h*64+d)
// Vt:  [768][4096] bf16 (row = h*64+d). Ob out: [4096][768] bf16 = o0 - exp(lam_h)*o1.
__global__ __launch_bounds__(256, 3) void k_attn2(const u16* __restrict__ QKb,
                                                  const u16* __restrict__ Vt,
                                                  const float* __restrict__ lamp,
                                                  u16* __restrict__ Ob) {
  const int qt = blockIdx.x, h = blockIdx.y, b = blockIdx.z;
  __shared__ u16 Ks[2][4096];  // [phase][64 rows x 64 d], swizzled 128B rows
  __shared__ u16 Vs[4096];     // [64 d-rows x 64 kv], swizzled
  __shared__ u16 Ps[4][1024];  // per-wave P scratch [16 q x 64 kv], swizzled
  const int t = threadIdx.x, w = t >> 6, l = t & 63;
  const int la = l & 15, lg = l >> 4;

  // Q fragments, both phases (wave w owns q rows qt*64+w*16 .. +15)
  const u16* qrow =
      QKb + (u64)(b * N_ + qt * 64 + w * 16 + la) * 3072 + h * 64 + lg * 8;
  bf16x8 qf00 = *(const bf16x8*)(qrow);
  bf16x8 qf01 = *(const bf16x8*)(qrow + 32);
  bf16x8 qf10 = *(const bf16x8*)(qrow + 768);
  bf16x8 qf11 = *(const bf16x8*)(qrow + 800);

  f32x4 oacc[2][4];
#pragma unroll
  for (int p = 0; p < 2; p++)
#pragma unroll
    for (int i = 0; i < 4; i++) oacc[p][i] = f32x4{0.f, 0.f, 0.f, 0.f};
  float m_run[2] = {-1e30f, -1e30f}, l_run[2] = {0.f, 0.f};

  // staging geometry: 512 16B-chunks/tile, thread covers chunks t and t+256
  const int rA = t >> 3, cb = (t & 7) << 4;
  const u32 swA = (u32)(rA * 128 + (cb ^ ((rA & 7) << 4)));  // chunk B = swA + 4096
  const char* kg = (const char*)(QKb + (u64)(b * N_ + rA) * 3072 + 1536 + h * 64) + cb;
  const char* vg = (const char*)(Vt + (u64)(h * 64 + rA) * M_ + b * N_) + cb;
  const u64 KR32 = (u64)32 * 3072 * 2;  // +32 rows (bytes)
  const u64 VR32 = (u64)32 * M_ * 2;
  const u64 KSTEP = (u64)64 * 3072 * 2;

  uint4 rk0A, rk0B, rk1A, rk1B, rvA, rvB;
#define ATTN_LOADS()                             \
  do {                                           \
    rk0A = *(const uint4*)(kg);                  \
    rk0B = *(const uint4*)(kg + KR32);           \
    rk1A = *(const uint4*)(kg + 1536);           \
    rk1B = *(const uint4*)(kg + 1536 + KR32);    \
    rvA = *(const uint4*)(vg);                   \
    rvB = *(const uint4*)(vg + VR32);            \
  } while (0)

  ATTN_LOADS();

  char* ks0 = (char*)Ks[0];
  char* ks1 = (char*)Ks[1];
  char* vsp = (char*)Vs;
  char* pw = (char*)Ps[w];
  const int sw2 = (la & 7) << 4;
  const float SCALE = 0.18033688f;  // 0.125 * log2(e)

  for (int kt = 0; kt < 32; kt++) {
    asm volatile("s_waitcnt vmcnt(0)" ::: "memory");
    __builtin_amdgcn_sched_barrier(0);
    *(uint4*)(ks0 + swA) = rk0A;
    *(uint4*)(ks0 + swA + 4096) = rk0B;
    *(uint4*)(ks1 + swA) = rk1A;
    *(uint4*)(ks1 + swA + 4096) = rk1B;
    *(uint4*)(vsp + swA) = rvA;
    *(uint4*)(vsp + swA + 4096) = rvB;
    asm volatile("s_waitcnt lgkmcnt(0)" ::: "memory");
    __builtin_amdgcn_s_barrier();
    kg += KSTEP;
    vg += 128;
    if (kt < 31) ATTN_LOADS();  // prefetch next tile; lands during compute
    __builtin_amdgcn_sched_barrier(0);

#pragma unroll
    for (int p = 0; p < 2; p++) {
      const char* ksp = p ? ks1 : ks0;
      bf16x8 q0 = p ? qf10 : qf00;
      bf16x8 q1 = p ? qf11 : qf01;
      // S^T[kv][q] = K @ Q^T  (lane: q=la, kv = c*16 + lg*4 + j)
      f32x4 st[4];
#pragma unroll
      for (int c = 0; c < 4; c++) {
        int row = c * 16 + la;
        int sw = (row & 7) << 4;
        bf16x8 kf0 = *(const bf16x8*)(ksp + row * 128 + ((lg * 16) ^ sw));
        bf16x8 kf1 = *(const bf16x8*)(ksp + row * 128 + ((64 + lg * 16) ^ sw));
        f32x4 z = f32x4{0.f, 0.f, 0.f, 0.f};
        z = __builtin_amdgcn_mfma_f32_16x16x32_bf16(kf0, q0, z, 0, 0, 0);
        z = __builtin_amdgcn_mfma_f32_16x16x32_bf16(kf1, q1, z, 0, 0, 0);
        st[c] = z * SCALE;  // log2-domain scores
      }
      float pmax = -1e30f;
#pragma unroll
      for (int c = 0; c < 4; c++)
#pragma unroll
        for (int j = 0; j < 4; j++) pmax = fmaxf(pmax, st[c][j]);
      pmax = fmaxf(pmax, __shfl_xor(pmax, 16, 64));
      pmax = fmaxf(pmax, __shfl_xor(pmax, 32, 64));
      float mr = m_run[p];
      if (__any(pmax - mr > 8.f)) {  // T13 defer-max: rescale only on real growth
        float mnew = fmaxf(mr, pmax);
        float corr = fexp2(mr - mnew);
        l_run[p] *= corr;
        float cT0 = __shfl(corr, lg * 4 + 0, 64);
        float cT1 = __shfl(corr, lg * 4 + 1, 64);
        float cT2 = __shfl(corr, lg * 4 + 2, 64);
        float cT3 = __shfl(corr, lg * 4 + 3, 64);
#pragma unroll
        for (int cd = 0; cd < 4; cd++) {
          oacc[p][cd][0] *= cT0;
          oacc[p][cd][1] *= cT1;
          oacc[p][cd][2] *= cT2;
          oacc[p][cd][3] *= cT3;
        }
        m_run[p] = mnew;
        mr = mnew;
      }
      float ls = 0.f;
#pragma unroll
      for (int c = 0; c < 4; c++)
#pragma unroll
        for (int j = 0; j < 4; j++) {
          float e = fexp2(st[c][j] - mr);
          st[c][j] = e;
          ls += e;
        }
      ls += __shfl_xor(ls, 16, 64);
      ls += __shfl_xor(ls, 32, 64);
      l_run[p] += ls;
      // P -> per-wave LDS as packed bf16 pairs (8 x ds_write_b32)
#pragma unroll
      for (int c = 0; c < 4; c++) {
        u32 lo = pack_bf16(st[c][0], st[c][1]);
        u32 hi = pack_bf16(st[c][2], st[c][3]);
        int kvb = c * 32 + lg * 8;
        *(u32*)(pw + la * 128 + (kvb ^ sw2)) = lo;
        *(u32*)(pw + la * 128 + ((kvb + 4) ^ sw2)) = hi;
      }
      bf16x8 pf0 = *(const bf16x8*)(pw + la * 128 + ((lg * 16) ^ sw2));
      bf16x8 pf1 = *(const bf16x8*)(pw + la * 128 + ((64 + lg * 16) ^ sw2));
#pragma unroll
      for (int cd = 0; cd < 4; cd++) {
        int row = cd * 16 + la;
        int sw = (row & 7) << 4;
        bf16x8 v0 = *(const bf16x8*)(vsp + row * 128 + ((lg * 16) ^ sw));
        bf16x8 v1 = *(const bf16x8*)(vsp + row * 128 + ((64 + lg * 16) ^ sw));
        oacc[p][cd] =
            __builtin_amdgcn_mfma_f32_16x16x32_bf16(pf0, v0, oacc[p][cd], 0, 0, 0);
        oacc[p][cd] =
            __builtin_amdgcn_mfma_f32_16x16x32_bf16(pf1, v1, oacc[p][cd], 0, 0, 0);
      }
    }
    __builtin_amdgcn_s_barrier();
  }

  // epilogue: fused combine  Ob = o0/l0 - exp(lam)*o1/l1
  float lam = __expf(lamp[h]);
  float i0 = 1.f / l_run[0];
  float i1 = 1.f / l_run[1];
  float s0[4], s1[4];
#pragma unroll
  for (int j = 0; j < 4; j++) {
    s0[j] = __shfl(i0, lg * 4 + j, 64);
    s1[j] = __shfl(i1, lg * 4 + j, 64);
  }
  u16* Og = Ob + (u64)(b * N_ + qt * 64 + w * 16) * C_ + h * 64;
#pragma unroll
  for (int cd = 0; cd < 4; cd++) {
    int dcol = cd * 16 + la;
#pragma unroll
    for (int j = 0; j < 4; j++) {
      float v = oacc[0][cd][j] * s0[j] - lam * (oacc[1][cd][j] * s1[j]);
      Og[(u64)(lg * 4 + j) * C_ + dcol] = f2bf(v);
    }
  }
}

extern "C" void kernel_launch(void* const* d_in, const int* in_sizes, int n_in,
                              void* d_out, int out_size, void* d_ws, size_t ws_size,
                              hipStream_t stream) {
  const float* x = (const float*)d_in[0];
  const float* Wq = (const float*)d_in[1];
  const float* Wk = (const float*)d_in[2];
  const float* Wv = (const float*)d_in[3];
  const float* lamp = (const float*)d_in[4];
  const float* Wo = (const float*)d_in[5];
  const float* bo = (const float*)d_in[6];

  char* ws = (char*)d_ws;
  u16* xb = (u16*)ws;    ws += (u64)M_ * C_ * 2;       // x bf16 [4096][768]
  u16* wqkt = (u16*)ws;  ws += (u64)4 * C_ * C_ * 2;   // [Wq^T;Wk^T] [3072][768]
  u16* wvo = (u16*)ws;   ws += (u64)2 * C_ * C_ * 2;   // [Wv^T;Wo^T] [1536][768]
  u16* QKb = (u16*)ws;   ws += (u64)M_ * 4 * C_ * 2;   // [4096][3072]
  u16* Vt = (u16*)ws;    ws += (u64)C_ * M_ * 2;       // V^T [768][4096]
  u16* Ob = (u16*)ws;    ws += (u64)M_ * C_ * 2;       // combined [4096][768]
  u16* wvt = wvo;
  u16* wot = wvo + (u64)C_ * C_;

  k_cvt4<<<dim3(M_ * C_ / 4 / 256), 256, 0, stream>>>(x, xb, M_ * C_ / 4);
  k_tconv2<<<dim3(48, 24, 2), dim3(32, 8), 0, stream>>>(Wq, Wk, wqkt, 768, 1536);
  k_tconv2<<<dim3(24, 24, 2), dim3(32, 8), 0, stream>>>(Wv, Wo, wvo, 768, 768);
  k_gemm<0><<<dim3(32, 24), 256, 0, stream>>>(xb, wqkt, QKb, nullptr, M_, 3072, 768);
  k_gemm<1><<<dim3(32, 6), 256, 0, stream>>>(xb, wvt, Vt, nullptr, M_, 768, 768);
  k_attn2<<<dim3(32, 12, 2), 256, 0, stream>>>(QKb, Vt, lamp, Ob);
  k_gemm<2><<<dim3(32, 6), 256, 0, stream>>>(Ob, wot, d_out, bo, M_, 768, 768);
}

// Round 3
// 154.459 us; speedup vs baseline: 1.4532x; 1.0798x over previous
//
#include <hip/hip_runtime.h>

typedef unsigned short u16;
typedef unsigned int u32;
typedef unsigned long long u64;
typedef __bf16 bf16x8 __attribute__((ext_vector_type(8)));
typedef float f32x4 __attribute__((ext_vector_type(4)));

#define B_ 2
#define N_ 2048
#define C_ 768
#define H_ 12
#define M_ 4096  // B_*N_
#define SCALE_LOG2 0.18033688011112042f  // 0.125 * log2(e), folded into Q

static __device__ __forceinline__ u16 f2bf(float f) {
  u32 u = __builtin_bit_cast(u32, f);
  u32 r = u + 0x7fffu + ((u >> 16) & 1u);  // RNE
  return (u16)(r >> 16);
}
static __device__ __forceinline__ float fexp2(float x) {
#if __has_builtin(__builtin_amdgcn_exp2f)
  return __builtin_amdgcn_exp2f(x);
#else
  return __expf(x * 0.6931471805599453f);
#endif
}
static __device__ __forceinline__ u32 pack_bf16(float a, float b) {
  u32 r;
  asm("v_cvt_pk_bf16_f32 %0, %1, %2" : "=v"(r) : "v"(a), "v"(b));
  return r;
}
static __device__ __forceinline__ float max3f(float a, float b, float c) {
  float r;
  asm("v_max3_f32 %0, %1, %2, %3" : "=v"(r) : "v"(a), "v"(b), "v"(c));
  return r;
}

// async global->LDS, 16B per lane; LDS dest is wave-uniform base (HW adds lane*16)
static __device__ __forceinline__ void gload16(const void* g, void* lds_base) {
  __builtin_amdgcn_global_load_lds(
      (__attribute__((address_space(1))) void*)(u64)(g),
      (__attribute__((address_space(3))) void*)(u32)(u64)(lds_base), 16, 0, 0);
}

// ---------------- fp32 -> bf16 elementwise (x) ----------------
__global__ __launch_bounds__(256) void k_cvt4(const float* __restrict__ x,
                                              u16* __restrict__ xb, int n4) {
  int i = blockIdx.x * 256 + threadIdx.x;
  if (i >= n4) return;
  float4 v = ((const float4*)x)[i];
  ushort4 o;
  o.x = f2bf(v.x); o.y = f2bf(v.y); o.z = f2bf(v.z); o.w = f2bf(v.w);
  ((ushort4*)xb)[i] = o;
}

// ---------------- W[K][N] fp32 -> Wt[N][K] bf16, z selects (src, dst slab) ----------------
__global__ __launch_bounds__(256) void k_tconv2(const float* __restrict__ W0,
                                                const float* __restrict__ W1,
                                                u16* __restrict__ Wt, int K, int N) {
  const float* W = blockIdx.z ? W1 : W0;
  u16* dst = Wt + (u64)blockIdx.z * N * K;
  __shared__ float t[32][33];
  int n0 = blockIdx.x * 32, k0 = blockIdx.y * 32;
  int tx = threadIdx.x, ty = threadIdx.y;  // 32 x 8
#pragma unroll
  for (int i = 0; i < 4; i++)
    t[ty + i * 8][tx] = W[(u64)(k0 + ty + i * 8) * N + n0 + tx];
  __syncthreads();
#pragma unroll
  for (int i = 0; i < 4; i++)
    dst[(u64)(n0 + ty + i * 8) * K + k0 + tx] = f2bf(t[tx][ty + i * 8]);
}

// ---------------- fused QKV projection GEMM ----------------
// blockIdx.y < 24: QK part -> QKb [4096][3072] bf16, Q cols (<1536) pre-scaled
// blockIdx.y >= 24: V part -> Vt [768][4096] bf16 (transposed write)
__global__ __launch_bounds__(256) void k_gemm_qkv(const u16* __restrict__ A,
                                                  const u16* __restrict__ WQK,
                                                  const u16* __restrict__ WV,
                                                  u16* __restrict__ QKb,
                                                  u16* __restrict__ Vtout) {
  __shared__ u16 As[128 * 32];
  __shared__ u16 Bs[128 * 32];
  const int t = threadIdx.x;
  const int w = t >> 6, l = t & 63;
  const int wr = w >> 1, wc = w & 1;
  const int la = l & 15, lg = l >> 4;
  const int srow = l >> 2, scb = (l & 3) << 4;
  const int by = blockIdx.y;
  const bool isV = by >= 24;

  f32x4 acc[4][4];
#pragma unroll
  for (int i = 0; i < 4; i++)
#pragma unroll
    for (int j = 0; j < 4; j++) acc[i][j] = f32x4{0.f, 0.f, 0.f, 0.f};

  const u16* Ag = A + (u64)(blockIdx.x * 128) * 768;
  const u16* Bg = isV ? WV + (u64)((by - 24) * 128) * 768 : WQK + (u64)(by * 128) * 768;

  for (int k0 = 0; k0 < 768; k0 += 32) {
#pragma unroll
    for (int j = 0; j < 2; j++) {
      int r = (w * 2 + j) * 16 + srow;
      gload16((const char*)(Ag + (u64)r * 768 + k0) + scb, (char*)As + (w * 2 + j) * 1024);
      gload16((const char*)(Bg + (u64)r * 768 + k0) + scb, (char*)Bs + (w * 2 + j) * 1024);
    }
    __syncthreads();
    bf16x8 af[4], bfr[4];
#pragma unroll
    for (int m = 0; m < 4; m++)
      af[m] = *(const bf16x8*)(As + (wr * 64 + m * 16 + la) * 32 + lg * 8);
#pragma unroll
    for (int n = 0; n < 4; n++)
      bfr[n] = *(const bf16x8*)(Bs + (wc * 64 + n * 16 + la) * 32 + lg * 8);
#pragma unroll
    for (int m = 0; m < 4; m++)
#pragma unroll
      for (int n = 0; n < 4; n++)
        acc[m][n] =
            __builtin_amdgcn_mfma_f32_16x16x32_bf16(af[m], bfr[n], acc[m][n], 0, 0, 0);
    __syncthreads();
  }

#pragma unroll
  for (int m = 0; m < 4; m++) {
#pragma unroll
    for (int n = 0; n < 4; n++) {
      int grow0 = blockIdx.x * 128 + wr * 64 + m * 16 + lg * 4;
      if (!isV) {
        int gcol = by * 128 + wc * 64 + n * 16 + la;
        float sc = (gcol < 1536) ? SCALE_LOG2 : 1.0f;  // pre-scale Q columns
#pragma unroll
        for (int j = 0; j < 4; j++)
          QKb[(u64)(grow0 + j) * 3072 + gcol] = f2bf(acc[m][n][j] * sc);
      } else {
        int gcol = (by - 24) * 128 + wc * 64 + n * 16 + la;
        ushort4 o;
        o.x = f2bf(acc[m][n][0]); o.y = f2bf(acc[m][n][1]);
        o.z = f2bf(acc[m][n][2]); o.w = f2bf(acc[m][n][3]);
        *(ushort4*)(Vtout + (u64)gcol * M_ + grow0) = o;
      }
    }
  }
}

// ---------------- out-projection GEMM: C fp32 = A[M,768] @ Wt[768,768]^T + bias ----------------
__global__ __launch_bounds__(256) void k_gemm_out(const u16* __restrict__ A,
                                                  const u16* __restrict__ Bt,
                                                  float* __restrict__ Cout,
                                                  const float* __restrict__ bias) {
  __shared__ u16 As[128 * 32];
  __shared__ u16 Bs[128 * 32];
  const int t = threadIdx.x;
  const int w = t >> 6, l = t & 63;
  const int wr = w >> 1, wc = w & 1;
  const int la = l & 15, lg = l >> 4;
  const int srow = l >> 2, scb = (l & 3) << 4;

  f32x4 acc[4][4];
#pragma unroll
  for (int i = 0; i < 4; i++)
#pragma unroll
    for (int j = 0; j < 4; j++) acc[i][j] = f32x4{0.f, 0.f, 0.f, 0.f};

  const u16* Ag = A + (u64)(blockIdx.x * 128) * 768;
  const u16* Bg = Bt + (u64)(blockIdx.y * 128) * 768;

  for (int k0 = 0; k0 < 768; k0 += 32) {
#pragma unroll
    for (int j = 0; j < 2; j++) {
      int r = (w * 2 + j) * 16 + srow;
      gload16((const char*)(Ag + (u64)r * 768 + k0) + scb, (char*)As + (w * 2 + j) * 1024);
      gload16((const char*)(Bg + (u64)r * 768 + k0) + scb, (char*)Bs + (w * 2 + j) * 1024);
    }
    __syncthreads();
    bf16x8 af[4], bfr[4];
#pragma unroll
    for (int m = 0; m < 4; m++)
      af[m] = *(const bf16x8*)(As + (wr * 64 + m * 16 + la) * 32 + lg * 8);
#pragma unroll
    for (int n = 0; n < 4; n++)
      bfr[n] = *(const bf16x8*)(Bs + (wc * 64 + n * 16 + la) * 32 + lg * 8);
#pragma unroll
    for (int m = 0; m < 4; m++)
#pragma unroll
      for (int n = 0; n < 4; n++)
        acc[m][n] =
            __builtin_amdgcn_mfma_f32_16x16x32_bf16(af[m], bfr[n], acc[m][n], 0, 0, 0);
    __syncthreads();
  }

#pragma unroll
  for (int m = 0; m < 4; m++) {
#pragma unroll
    for (int n = 0; n < 4; n++) {
      int grow0 = blockIdx.x * 128 + wr * 64 + m * 16 + lg * 4;
      int gcol = blockIdx.y * 128 + wc * 64 + n * 16 + la;
      float bb = bias[gcol];
#pragma unroll
      for (int j = 0; j < 4; j++)
        Cout[(u64)(grow0 + j) * 768 + gcol] = acc[m][n][j] + bb;
    }
  }
}

// ---------------- fused dual-phase flash attention + combine (8-wave: wave-per-phase) ----------------
// QKb: [4096][3072] bf16 (Q cols p*768+h*64+d pre-scaled by SCALE_LOG2; K cols 1536+p*768+h*64+d)
// Vt:  [768][4096] bf16 (row = h*64+d). Ob out: [4096][768] bf16 = o0 - exp(lam_h)*o1.
// Block: 512 threads. Wave w: phase p=w>>2, q-rows qt*64 + (w&3)*16 .. +15.
__global__ __launch_bounds__(512, 6) void k_attn3(const u16* __restrict__ QKb,
                                                  const u16* __restrict__ Vt,
                                                  const float* __restrict__ lamp,
                                                  u16* __restrict__ Ob) {
  const int qt = blockIdx.x, h = blockIdx.y, b = blockIdx.z;
  // smem: Ks[2] 0..16K, Vs 16K..24K, Ps[8] 24K..40K; epilogue reuses 0..17K as f32
  __shared__ __align__(16) char smem[40960];
  char* ks0 = smem;
  char* ks1 = smem + 8192;
  char* vsp = smem + 16384;
  const int t = threadIdx.x, w = t >> 6, l = t & 63;
  const int p = w >> 2, wq = w & 3;
  char* pw = smem + 24576 + w * 2048;
  const int la = l & 15, lg = l >> 4;
  const int sw2 = (la & 7) << 4;

  // Q fragments for this wave's phase (already scaled by 0.125*log2e)
  const u16* qrow =
      QKb + (u64)(b * N_ + qt * 64 + wq * 16 + la) * 3072 + p * 768 + h * 64 + lg * 8;
  bf16x8 q0 = *(const bf16x8*)(qrow);
  bf16x8 q1 = *(const bf16x8*)(qrow + 32);

  f32x4 oacc[4];
#pragma unroll
  for (int i = 0; i < 4; i++) oacc[i] = f32x4{0.f, 0.f, 0.f, 0.f};
  float m_run = -1e30f, l_run = 0.f;

  // staging: 512 threads x 3 chunks of 16B (K phase0, K phase1, V), 8KB tiles each
  const int rA = t >> 3, cbs = (t & 7) << 4;
  const u32 swA = (u32)(rA * 128 + (cbs ^ ((rA & 7) << 4)));
  const char* kg = (const char*)(QKb + (u64)(b * N_ + rA) * 3072 + 1536 + h * 64) + cbs;
  const char* vg = (const char*)(Vt + (u64)(h * 64 + rA) * M_ + b * N_) + cbs;
  const u64 KSTEP = (u64)64 * 3072 * 2;

  uint4 rk0, rk1, rv;
  rk0 = *(const uint4*)(kg);
  rk1 = *(const uint4*)(kg + 1536);
  rv = *(const uint4*)(vg);

  const char* ksp = p ? ks1 : ks0;

  for (int kt = 0; kt < 32; kt++) {
    asm volatile("s_waitcnt vmcnt(0)" ::: "memory");
    __builtin_amdgcn_sched_barrier(0);
    *(uint4*)(ks0 + swA) = rk0;
    *(uint4*)(ks1 + swA) = rk1;
    *(uint4*)(vsp + swA) = rv;
    asm volatile("s_waitcnt lgkmcnt(0)" ::: "memory");
    __builtin_amdgcn_s_barrier();
    kg += KSTEP;
    vg += 128;
    if (kt < 31) {  // prefetch next tile; lands during compute
      rk0 = *(const uint4*)(kg);
      rk1 = *(const uint4*)(kg + 1536);
      rv = *(const uint4*)(vg);
    }
    __builtin_amdgcn_sched_barrier(0);

    // S^T[kv][q] = K @ Q^T  (lane: q=la, kv = c*16 + lg*4 + j), log2-domain
    f32x4 st[4];
#pragma unroll
    for (int c = 0; c < 4; c++) {
      int row = c * 16 + la;
      int sw = (row & 7) << 4;
      bf16x8 kf0 = *(const bf16x8*)(ksp + row * 128 + ((lg * 16) ^ sw));
      bf16x8 kf1 = *(const bf16x8*)(ksp + row * 128 + ((64 + lg * 16) ^ sw));
      f32x4 z = f32x4{0.f, 0.f, 0.f, 0.f};
      z = __builtin_amdgcn_mfma_f32_16x16x32_bf16(kf0, q0, z, 0, 0, 0);
      z = __builtin_amdgcn_mfma_f32_16x16x32_bf16(kf1, q1, z, 0, 0, 0);
      st[c] = z;
    }
    // row max via v_max3 tree
    float m0 = max3f(st[0][0], st[0][1], st[0][2]);
    float m1 = max3f(st[0][3], st[1][0], st[1][1]);
    float m2 = max3f(st[1][2], st[1][3], st[2][0]);
    float m3 = max3f(st[2][1], st[2][2], st[2][3]);
    float m4 = max3f(st[3][0], st[3][1], st[3][2]);
    float pmax = fmaxf(max3f(m0, m1, m2), max3f(m3, m4, st[3][3]));
    pmax = fmaxf(pmax, __shfl_xor(pmax, 16, 64));
    pmax = fmaxf(pmax, __shfl_xor(pmax, 32, 64));
    if (__any(pmax - m_run > 8.f)) {  // T13 defer-max
      float mnew = fmaxf(m_run, pmax);
      float corr = fexp2(m_run - mnew);
      l_run *= corr;
      float cT0 = __shfl(corr, lg * 4 + 0, 64);
      float cT1 = __shfl(corr, lg * 4 + 1, 64);
      float cT2 = __shfl(corr, lg * 4 + 2, 64);
      float cT3 = __shfl(corr, lg * 4 + 3, 64);
#pragma unroll
      for (int cd = 0; cd < 4; cd++) {
        oacc[cd][0] *= cT0;
        oacc[cd][1] *= cT1;
        oacc[cd][2] *= cT2;
        oacc[cd][3] *= cT3;
      }
      m_run = mnew;
    }
    float ls = 0.f;
#pragma unroll
    for (int c = 0; c < 4; c++)
#pragma unroll
      for (int j = 0; j < 4; j++) {
        float e = fexp2(st[c][j] - m_run);
        st[c][j] = e;
        ls += e;
      }
    ls += __shfl_xor(ls, 16, 64);
    ls += __shfl_xor(ls, 32, 64);
    l_run += ls;
    // P -> per-wave LDS as packed bf16, 4 x ds_write_b64 (swizzle keeps pairs adjacent)
#pragma unroll
    for (int c = 0; c < 4; c++) {
      uint2 pr;
      pr.x = pack_bf16(st[c][0], st[c][1]);
      pr.y = pack_bf16(st[c][2], st[c][3]);
      int kvb = c * 32 + lg * 8;
      *(uint2*)(pw + la * 128 + (kvb ^ sw2)) = pr;
    }
    bf16x8 pf0 = *(const bf16x8*)(pw + la * 128 + ((lg * 16) ^ sw2));
    bf16x8 pf1 = *(const bf16x8*)(pw + la * 128 + ((64 + lg * 16) ^ sw2));
#pragma unroll
    for (int cd = 0; cd < 4; cd++) {
      int row = cd * 16 + la;
      int sw = (row & 7) << 4;
      bf16x8 v0 = *(const bf16x8*)(vsp + row * 128 + ((lg * 16) ^ sw));
      bf16x8 v1 = *(const bf16x8*)(vsp + row * 128 + ((64 + lg * 16) ^ sw));
      oacc[cd] = __builtin_amdgcn_mfma_f32_16x16x32_bf16(pf0, v0, oacc[cd], 0, 0, 0);
      oacc[cd] = __builtin_amdgcn_mfma_f32_16x16x32_bf16(pf1, v1, oacc[cd], 0, 0, 0);
    }
    __builtin_amdgcn_s_barrier();
  }

  // epilogue: phase-1 waves publish lam*o1/l1 via LDS; phase-0 waves combine & store
  float inv = 1.f / l_run;
  float s0 = __shfl(inv, lg * 4 + 0, 64);
  float s1 = __shfl(inv, lg * 4 + 1, 64);
  float s2 = __shfl(inv, lg * 4 + 2, 64);
  float s3 = __shfl(inv, lg * 4 + 3, 64);
  float sj[4] = {s0, s1, s2, s3};
  float* cmb = (float*)smem + wq * (16 * 66);
  __syncthreads();  // all loop-LDS traffic drained before aliasing reuse
  if (p == 1) {
    float lam = __expf(lamp[h]);
#pragma unroll
    for (int cd = 0; cd < 4; cd++)
#pragma unroll
      for (int j = 0; j < 4; j++)
        cmb[(lg * 4 + j) * 66 + cd * 16 + la] = lam * oacc[cd][j] * sj[j];
  }
  __syncthreads();
  if (p == 0) {
    u16* Og = Ob + (u64)(b * N_ + qt * 64 + wq * 16) * C_ + h * 64;
#pragma unroll
    for (int cd = 0; cd < 4; cd++)
#pragma unroll
      for (int j = 0; j < 4; j++) {
        float v = oacc[cd][j] * sj[j] - cmb[(lg * 4 + j) * 66 + cd * 16 + la];
        Og[(u64)(lg * 4 + j) * C_ + cd * 16 + la] = f2bf(v);
      }
  }
}

extern "C" void kernel_launch(void* const* d_in, const int* in_sizes, int n_in,
                              void* d_out, int out_size, void* d_ws, size_t ws_size,
                              hipStream_t stream) {
  const float* x = (const float*)d_in[0];
  const float* Wq = (const float*)d_in[1];
  const float* Wk = (const float*)d_in[2];
  const float* Wv = (const float*)d_in[3];
  const float* lamp = (const float*)d_in[4];
  const float* Wo = (const float*)d_in[5];
  const float* bo = (const float*)d_in[6];

  char* ws = (char*)d_ws;
  u16* xb = (u16*)ws;    ws += (u64)M_ * C_ * 2;       // x bf16 [4096][768]
  u16* wqkt = (u16*)ws;  ws += (u64)4 * C_ * C_ * 2;   // [Wq^T;Wk^T] [3072][768]
  u16* wvo = (u16*)ws;   ws += (u64)2 * C_ * C_ * 2;   // [Wv^T;Wo^T] [1536][768]
  u16* QKb = (u16*)ws;   ws += (u64)M_ * 4 * C_ * 2;   // [4096][3072]
  u16* Vt = (u16*)ws;    ws += (u64)C_ * M_ * 2;       // V^T [768][4096]
  u16* Ob = (u16*)ws;    ws += (u64)M_ * C_ * 2;       // combined [4096][768]
  u16* wvt = wvo;
  u16* wot = wvo + (u64)C_ * C_;

  k_cvt4<<<dim3(M_ * C_ / 4 / 256), 256, 0, stream>>>(x, xb, M_ * C_ / 4);
  k_tconv2<<<dim3(48, 24, 2), dim3(32, 8), 0, stream>>>(Wq, Wk, wqkt, 768, 1536);
  k_tconv2<<<dim3(24, 24, 2), dim3(32, 8), 0, stream>>>(Wv, Wo, wvo, 768, 768);
  k_gemm_qkv<<<dim3(32, 30), 256, 0, stream>>>(xb, wqkt, wvt, QKb, Vt);
  k_attn3<<<dim3(32, 12, 2), 512, 0, stream>>>(QKb, Vt, lamp, Ob);
  k_gemm_out<<<dim3(32, 6), 256, 0, stream>>>(Ob, wot, (float*)d_out, bo);
}

// Round 5
// 152.039 us; speedup vs baseline: 1.4763x; 1.0159x over previous
//
#include <hip/hip_runtime.h>

typedef unsigned short u16;
typedef unsigned int u32;
typedef unsigned long long u64;
typedef __bf16 bf16x8 __attribute__((ext_vector_type(8)));
typedef float f32x4 __attribute__((ext_vector_type(4)));
typedef float f32x16 __attribute__((ext_vector_type(16)));

#define B_ 2
#define N_ 2048
#define C_ 768
#define H_ 12
#define M_ 4096  // B_*N_
#define SCALE_LOG2 0.18033688011112042f  // 0.125 * log2(e), folded into Q

static __device__ __forceinline__ u16 f2bf(float f) {
  u32 u = __builtin_bit_cast(u32, f);
  u32 r = u + 0x7fffu + ((u >> 16) & 1u);  // RNE
  return (u16)(r >> 16);
}
static __device__ __forceinline__ float fexp2(float x) {
#if __has_builtin(__builtin_amdgcn_exp2f)
  return __builtin_amdgcn_exp2f(x);
#else
  return __expf(x * 0.6931471805599453f);
#endif
}
static __device__ __forceinline__ u32 pack_bf16(float a, float b) {
  u32 r;
  asm("v_cvt_pk_bf16_f32 %0, %1, %2" : "=v"(r) : "v"(a), "v"(b));
  return r;
}

// async global->LDS, 16B per lane; LDS dest is wave-uniform base (HW adds lane*16)
static __device__ __forceinline__ void gload16(const void* g, void* lds_base) {
  __builtin_amdgcn_global_load_lds(
      (__attribute__((address_space(1))) void*)(u64)(g),
      (__attribute__((address_space(3))) void*)(u32)(u64)(lds_base), 16, 0, 0);
}

// ---------------- fp32 -> bf16 elementwise (x) ----------------
__global__ __launch_bounds__(256) void k_cvt4(const float* __restrict__ x,
                                              u16* __restrict__ xb, int n4) {
  int i = blockIdx.x * 256 + threadIdx.x;
  if (i >= n4) return;
  float4 v = ((const float4*)x)[i];
  ushort4 o;
  o.x = f2bf(v.x); o.y = f2bf(v.y); o.z = f2bf(v.z); o.w = f2bf(v.w);
  ((ushort4*)xb)[i] = o;
}

// ---------------- W[K][N] fp32 -> Wt[N][K] bf16, z selects (src, dst slab) ----------------
__global__ __launch_bounds__(256) void k_tconv2(const float* __restrict__ W0,
                                                const float* __restrict__ W1,
                                                u16* __restrict__ Wt, int K, int N) {
  const float* W = blockIdx.z ? W1 : W0;
  u16* dst = Wt + (u64)blockIdx.z * N * K;
  __shared__ float t[32][33];
  int n0 = blockIdx.x * 32, k0 = blockIdx.y * 32;
  int tx = threadIdx.x, ty = threadIdx.y;  // 32 x 8
#pragma unroll
  for (int i = 0; i < 4; i++)
    t[ty + i * 8][tx] = W[(u64)(k0 + ty + i * 8) * N + n0 + tx];
  __syncthreads();
#pragma unroll
  for (int i = 0; i < 4; i++)
    dst[(u64)(n0 + ty + i * 8) * K + k0 + tx] = f2bf(t[tx][ty + i * 8]);
}

// ---------------- fused QKV projection GEMM ----------------
// blockIdx.y < 24: QK part -> QKb [4096][3072] bf16, Q cols (<1536) pre-scaled
// blockIdx.y >= 24: V part -> Vt [768][4096] bf16 (transposed write)
__global__ __launch_bounds__(256) void k_gemm_qkv(const u16* __restrict__ A,
                                                  const u16* __restrict__ WQK,
                                                  const u16* __restrict__ WV,
                                                  u16* __restrict__ QKb,
                                                  u16* __restrict__ Vtout) {
  __shared__ u16 As[128 * 32];
  __shared__ u16 Bs[128 * 32];
  const int t = threadIdx.x;
  const int w = t >> 6, l = t & 63;
  const int wr = w >> 1, wc = w & 1;
  const int la = l & 15, lg = l >> 4;
  const int srow = l >> 2, scb = (l & 3) << 4;
  const int by = blockIdx.y;
  const bool isV = by >= 24;

  f32x4 acc[4][4];
#pragma unroll
  for (int i = 0; i < 4; i++)
#pragma unroll
    for (int j = 0; j < 4; j++) acc[i][j] = f32x4{0.f, 0.f, 0.f, 0.f};

  const u16* Ag = A + (u64)(blockIdx.x * 128) * 768;
  const u16* Bg = isV ? WV + (u64)((by - 24) * 128) * 768 : WQK + (u64)(by * 128) * 768;

  for (int k0 = 0; k0 < 768; k0 += 32) {
#pragma unroll
    for (int j = 0; j < 2; j++) {
      int r = (w * 2 + j) * 16 + srow;
      gload16((const char*)(Ag + (u64)r * 768 + k0) + scb, (char*)As + (w * 2 + j) * 1024);
      gload16((const char*)(Bg + (u64)r * 768 + k0) + scb, (char*)Bs + (w * 2 + j) * 1024);
    }
    __syncthreads();
    bf16x8 af[4], bfr[4];
#pragma unroll
    for (int m = 0; m < 4; m++)
      af[m] = *(const bf16x8*)(As + (wr * 64 + m * 16 + la) * 32 + lg * 8);
#pragma unroll
    for (int n = 0; n < 4; n++)
      bfr[n] = *(const bf16x8*)(Bs + (wc * 64 + n * 16 + la) * 32 + lg * 8);
#pragma unroll
    for (int m = 0; m < 4; m++)
#pragma unroll
      for (int n = 0; n < 4; n++)
        acc[m][n] =
            __builtin_amdgcn_mfma_f32_16x16x32_bf16(af[m], bfr[n], acc[m][n], 0, 0, 0);
    __syncthreads();
  }

#pragma unroll
  for (int m = 0; m < 4; m++) {
#pragma unroll
    for (int n = 0; n < 4; n++) {
      int grow0 = blockIdx.x * 128 + wr * 64 + m * 16 + lg * 4;
      if (!isV) {
        int gcol = by * 128 + wc * 64 + n * 16 + la;
        float sc = (gcol < 1536) ? SCALE_LOG2 : 1.0f;  // pre-scale Q columns
#pragma unroll
        for (int j = 0; j < 4; j++)
          QKb[(u64)(grow0 + j) * 3072 + gcol] = f2bf(acc[m][n][j] * sc);
      } else {
        int gcol = (by - 24) * 128 + wc * 64 + n * 16 + la;
        ushort4 o;
        o.x = f2bf(acc[m][n][0]); o.y = f2bf(acc[m][n][1]);
        o.z = f2bf(acc[m][n][2]); o.w = f2bf(acc[m][n][3]);
        *(ushort4*)(Vtout + (u64)gcol * M_ + grow0) = o;
      }
    }
  }
}

// ---------------- out-projection GEMM: C fp32 = A[M,768] @ Wt[768,768]^T + bias ----------------
__global__ __launch_bounds__(256) void k_gemm_out(const u16* __restrict__ A,
                                                  const u16* __restrict__ Bt,
                                                  float* __restrict__ Cout,
                                                  const float* __restrict__ bias) {
  __shared__ u16 As[128 * 32];
  __shared__ u16 Bs[128 * 32];
  const int t = threadIdx.x;
  const int w = t >> 6, l = t & 63;
  const int wr = w >> 1, wc = w & 1;
  const int la = l & 15, lg = l >> 4;
  const int srow = l >> 2, scb = (l & 3) << 4;

  f32x4 acc[4][4];
#pragma unroll
  for (int i = 0; i < 4; i++)
#pragma unroll
    for (int j = 0; j < 4; j++) acc[i][j] = f32x4{0.f, 0.f, 0.f, 0.f};

  const u16* Ag = A + (u64)(blockIdx.x * 128) * 768;
  const u16* Bg = Bt + (u64)(blockIdx.y * 128) * 768;

  for (int k0 = 0; k0 < 768; k0 += 32) {
#pragma unroll
    for (int j = 0; j < 2; j++) {
      int r = (w * 2 + j) * 16 + srow;
      gload16((const char*)(Ag + (u64)r * 768 + k0) + scb, (char*)As + (w * 2 + j) * 1024);
      gload16((const char*)(Bg + (u64)r * 768 + k0) + scb, (char*)Bs + (w * 2 + j) * 1024);
    }
    __syncthreads();
    bf16x8 af[4], bfr[4];
#pragma unroll
    for (int m = 0; m < 4; m++)
      af[m] = *(const bf16x8*)(As + (wr * 64 + m * 16 + la) * 32 + lg * 8);
#pragma unroll
    for (int n = 0; n < 4; n++)
      bfr[n] = *(const bf16x8*)(Bs + (wc * 64 + n * 16 + la) * 32 + lg * 8);
#pragma unroll
    for (int m = 0; m < 4; m++)
#pragma unroll
      for (int n = 0; n < 4; n++)
        acc[m][n] =
            __builtin_amdgcn_mfma_f32_16x16x32_bf16(af[m], bfr[n], acc[m][n], 0, 0, 0);
    __syncthreads();
  }

#pragma unroll
  for (int m = 0; m < 4; m++) {
#pragma unroll
    for (int n = 0; n < 4; n++) {
      int grow0 = blockIdx.x * 128 + wr * 64 + m * 16 + lg * 4;
      int gcol = blockIdx.y * 128 + wc * 64 + n * 16 + la;
      float bb = bias[gcol];
#pragma unroll
      for (int j = 0; j < 4; j++)
        Cout[(u64)(grow0 + j) * 768 + gcol] = acc[m][n][j] + bb;
    }
  }
}

// ---------------- fused dual-phase flash attention + combine (32x32 MFMA, P via LDS) ----
// QKb: [4096][3072] bf16 (Q cols p*768+h*64+d pre-scaled; K cols 1536+p*768+h*64+d)
// Vt:  [768][4096] bf16 (row = h*64+d). Ob out: [4096][768] bf16 = o0 - exp(lam_h)*o1.
// 256 thr / 4 waves: wave w: phase p=w>>1, q-strip s=w&1 (32 q-rows each).
// Lane: ql=l&31, hh=l>>5.
__global__ __launch_bounds__(256, 3) void k_attn5(const u16* __restrict__ QKb,
                                                  const u16* __restrict__ Vt,
                                                  const float* __restrict__ lamp,
                                                  u16* __restrict__ Ob) {
  // XCD-aware bijective swizzle: 768 = 8 XCD * 96; blocks of one (b,h) share an XCD L2
  const int hw = blockIdx.x;
  const int wid = (hw & 7) * 96 + (hw >> 3);
  const int qt = wid & 31;
  const int hb = wid >> 5;
  const int h = hb % H_, b = hb / H_;

  // smem: Ks[2] 0..16K, Vs 16K..24K, Ps[4 waves x 4K] 24K..40K
  __shared__ __align__(16) char smem[40960];
  char* ks0 = smem;
  char* ks1 = smem + 8192;
  char* vsp = smem + 16384;
  const int t = threadIdx.x, w = t >> 6, l = t & 63;
  const int p = w >> 1, s = w & 1;
  const int ql = l & 31, hh = l >> 5;
  char* pw = smem + 24576 + w * 4096;
  const int swq = (ql & 7) << 4;

  // Q B-frags: 4 k-slices; q = qt*64+s*32+ql, d = 16c + 8*hh + j
  const u16* qrow =
      QKb + (u64)(b * N_ + qt * 64 + s * 32 + ql) * 3072 + p * 768 + h * 64 + hh * 8;
  bf16x8 qf[4];
#pragma unroll
  for (int c = 0; c < 4; c++) qf[c] = *(const bf16x8*)(qrow + 16 * c);

  f32x16 oacc0, oacc1;
#pragma unroll
  for (int r = 0; r < 16; r++) { oacc0[r] = 0.f; oacc1[r] = 0.f; }
  float m_run = -1e30f, l_run = 0.f;

  // staging: 256 thr x 2 rows (rA, rA+32) x 16B, swizzled
  const int rA = t >> 3, cbs = (t & 7) << 4;
  const u32 swA = (u32)(rA * 128 + (cbs ^ ((rA & 7) << 4)));
  const char* kg = (const char*)(QKb + (u64)(b * N_ + rA) * 3072 + 1536 + h * 64) + cbs;
  const char* vg = (const char*)(Vt + (u64)(h * 64 + rA) * M_ + b * N_) + cbs;
  const u64 KR32 = (u64)32 * 3072 * 2;
  const u64 VR32 = (u64)32 * M_ * 2;
  const u64 KSTEP = (u64)64 * 3072 * 2;

  uint4 rk0A, rk0B, rk1A, rk1B, rvA, rvB;
#define LOADS6()                              \
  do {                                        \
    rk0A = *(const uint4*)(kg);               \
    rk0B = *(const uint4*)(kg + KR32);        \
    rk1A = *(const uint4*)(kg + 1536);        \
    rk1B = *(const uint4*)(kg + 1536 + KR32); \
    rvA = *(const uint4*)(vg);                \
    rvB = *(const uint4*)(vg + VR32);         \
  } while (0)
  LOADS6();

  const char* ksp = p ? ks1 : ks0;
  // ds_read offsets per k-slice: logical byte 32c+16hh of a row, row-XOR swizzled
  int koff[4];
#pragma unroll
  for (int c = 0; c < 4; c++) koff[c] = (32 * c + 16 * hh) ^ swq;

  for (int kt = 0; kt < 32; kt++) {
    asm volatile("s_waitcnt vmcnt(0)" ::: "memory");
    __builtin_amdgcn_sched_barrier(0);
    *(uint4*)(ks0 + swA) = rk0A;
    *(uint4*)(ks0 + swA + 4096) = rk0B;
    *(uint4*)(ks1 + swA) = rk1A;
    *(uint4*)(ks1 + swA + 4096) = rk1B;
    *(uint4*)(vsp + swA) = rvA;
    *(uint4*)(vsp + swA + 4096) = rvB;
    asm volatile("s_waitcnt lgkmcnt(0)" ::: "memory");
    __builtin_amdgcn_s_barrier();
    kg += KSTEP;
    vg += 128;
    if (kt < 31) LOADS6();  // prefetch next tile; lands during compute
    __builtin_amdgcn_sched_barrier(0);

    // QK^T (swapped): S^T[kv][q]; kv-tiles 0,1; A=K rows kv, B=Q
    f32x16 st0, st1;
#pragma unroll
    for (int r = 0; r < 16; r++) { st0[r] = 0.f; st1[r] = 0.f; }
#pragma unroll
    for (int c = 0; c < 4; c++) {
      bf16x8 kf0 = *(const bf16x8*)(ksp + ql * 128 + koff[c]);
      bf16x8 kf1 = *(const bf16x8*)(ksp + (32 + ql) * 128 + koff[c]);
      st0 = __builtin_amdgcn_mfma_f32_32x32x16_bf16(kf0, qf[c], st0, 0, 0, 0);
      st1 = __builtin_amdgcn_mfma_f32_32x32x16_bf16(kf1, qf[c], st1, 0, 0, 0);
    }

    // row max over 32 in-lane values + cross-half combine (lane&31 = q)
    float mx[16];
#pragma unroll
    for (int r = 0; r < 16; r++) mx[r] = fmaxf(st0[r], st1[r]);
#pragma unroll
    for (int sd = 8; sd >= 1; sd >>= 1)
#pragma unroll
      for (int r = 0; r < sd; r++) mx[r] = fmaxf(mx[r], mx[r + sd]);
    float pmax = fmaxf(mx[0], __shfl_xor(mx[0], 32, 64));

    if (__any(pmax - m_run > 8.f)) {  // T13 defer-max
      float mnew = fmaxf(m_run, pmax);
      float corr = fexp2(m_run - mnew);
      l_run *= corr;
      float cT[16];
#pragma unroll
      for (int r = 0; r < 16; r++)
        cT[r] = __shfl(corr, (r & 3) + 8 * (r >> 2) + 4 * hh, 64);
#pragma unroll
      for (int r = 0; r < 16; r++) { oacc0[r] *= cT[r]; oacc1[r] *= cT[r]; }
      m_run = mnew;
    }
#pragma unroll
    for (int r = 0; r < 16; r++) {
      st0[r] = fexp2(st0[r] - m_run);
      st1[r] = fexp2(st1[r] - m_run);
    }
    float sm[16];
#pragma unroll
    for (int r = 0; r < 16; r++) sm[r] = st0[r] + st1[r];
#pragma unroll
    for (int sd = 8; sd >= 1; sd >>= 1)
#pragma unroll
      for (int r = 0; r < sd; r++) sm[r] += sm[r + sd];
    l_run += sm[0] + __shfl_xor(sm[0], 32, 64);

    // P -> wave-private LDS (addresses from the verified C/D map:
    // st0[r] = P[q=ql][kv=(r&3)+8(r>>2)+4hh], st1 same +32). Row = q, byte = 2*kv.
#pragma unroll
    for (int g = 0; g < 4; g++) {
      uint2 w0, w1;
      w0.x = pack_bf16(st0[4 * g + 0], st0[4 * g + 1]);
      w0.y = pack_bf16(st0[4 * g + 2], st0[4 * g + 3]);
      w1.x = pack_bf16(st1[4 * g + 0], st1[4 * g + 1]);
      w1.y = pack_bf16(st1[4 * g + 2], st1[4 * g + 3]);
      int bo = 16 * g + 8 * hh;
      *(uint2*)(pw + ql * 128 + (bo ^ swq)) = w0;
      *(uint2*)(pw + ql * 128 + ((64 + bo) ^ swq)) = w1;
    }
    // PV A-frags read back with the same contiguous convention as the V-load
    bf16x8 pa[4];
#pragma unroll
    for (int c = 0; c < 4; c++)
      pa[c] = *(const bf16x8*)(pw + ql * 128 + koff[c]);

    // PV: O[q][d] += P @ V ; d-tiles 0,1 ; B=V from Vs[d-row][kv-col]
#pragma unroll
    for (int c = 0; c < 4; c++) {
      bf16x8 vf0 = *(const bf16x8*)(vsp + ql * 128 + koff[c]);
      bf16x8 vf1 = *(const bf16x8*)(vsp + (32 + ql) * 128 + koff[c]);
      oacc0 = __builtin_amdgcn_mfma_f32_32x32x16_bf16(pa[c], vf0, oacc0, 0, 0, 0);
      oacc1 = __builtin_amdgcn_mfma_f32_32x32x16_bf16(pa[c], vf1, oacc1, 0, 0, 0);
    }
    __builtin_amdgcn_s_barrier();
  }

  // epilogue: phase-1 publishes lam*o1/l1 via LDS; phase-0 combines & stores
  float inv = 1.f / l_run;
  float iT[16];
#pragma unroll
  for (int r = 0; r < 16; r++)
    iT[r] = __shfl(inv, (r & 3) + 8 * (r >> 2) + 4 * hh, 64);
  float* cmb = (float*)smem;  // [64 q][64 d] f32 = 16KB
  __syncthreads();
  if (p == 1) {
    float lam = __expf(lamp[h]);
#pragma unroll
    for (int r = 0; r < 16; r++) {
      int qr = (r & 3) + 8 * (r >> 2) + 4 * hh;
      cmb[(s * 32 + qr) * 64 + ql] = lam * oacc0[r] * iT[r];
      cmb[(s * 32 + qr) * 64 + 32 + ql] = lam * oacc1[r] * iT[r];
    }
  }
  __syncthreads();
  if (p == 0) {
    u16* Og = Ob + (u64)(b * N_ + qt * 64 + s * 32) * C_ + h * 64;
#pragma unroll
    for (int r = 0; r < 16; r++) {
      int qr = (r & 3) + 8 * (r >> 2) + 4 * hh;
      float v0 = oacc0[r] * iT[r] - cmb[(s * 32 + qr) * 64 + ql];
      float v1 = oacc1[r] * iT[r] - cmb[(s * 32 + qr) * 64 + 32 + ql];
      Og[(u64)qr * C_ + ql] = f2bf(v0);
      Og[(u64)qr * C_ + 32 + ql] = f2bf(v1);
    }
  }
}

extern "C" void kernel_launch(void* const* d_in, const int* in_sizes, int n_in,
                              void* d_out, int out_size, void* d_ws, size_t ws_size,
                              hipStream_t stream) {
  const float* x = (const float*)d_in[0];
  const float* Wq = (const float*)d_in[1];
  const float* Wk = (const float*)d_in[2];
  const float* Wv = (const float*)d_in[3];
  const float* lamp = (const float*)d_in[4];
  const float* Wo = (const float*)d_in[5];
  const float* bo = (const float*)d_in[6];

  char* ws = (char*)d_ws;
  u16* xb = (u16*)ws;    ws += (u64)M_ * C_ * 2;       // x bf16 [4096][768]
  u16* wqkt = (u16*)ws;  ws += (u64)4 * C_ * C_ * 2;   // [Wq^T;Wk^T] [3072][768]
  u16* wvo = (u16*)ws;   ws += (u64)2 * C_ * C_ * 2;   // [Wv^T;Wo^T] [1536][768]
  u16* QKb = (u16*)ws;   ws += (u64)M_ * 4 * C_ * 2;   // [4096][3072]
  u16* Vt = (u16*)ws;    ws += (u64)C_ * M_ * 2;       // V^T [768][4096]
  u16* Ob = (u16*)ws;    ws += (u64)M_ * C_ * 2;       // combined [4096][768]
  u16* wvt = wvo;
  u16* wot = wvo + (u64)C_ * C_;

  k_cvt4<<<dim3(M_ * C_ / 4 / 256), 256, 0, stream>>>(x, xb, M_ * C_ / 4);
  k_tconv2<<<dim3(48, 24, 2), dim3(32, 8), 0, stream>>>(Wq, Wk, wqkt, 768, 1536);
  k_tconv2<<<dim3(24, 24, 2), dim3(32, 8), 0, stream>>>(Wv, Wo, wvo, 768, 768);
  k_gemm_qkv<<<dim3(32, 30), 256, 0, stream>>>(xb, wqkt, wvt, QKb, Vt);
  k_attn5<<<dim3(768), 256, 0, stream>>>(QKb, Vt, lamp, Ob);
  k_gemm_out<<<dim3(32, 6), 256, 0, stream>>>(Ob, wot, (float*)d_out, bo);
}